// Round 1
// baseline (1214.159 us; speedup 1.0000x reference)
//
#include <hip/hip_runtime.h>

// ResidualGNNLayer: h = x@W; gcn_norm scatter-add; +bias; LayerNorm; 0.5*h+0.5*x; relu
// N=100000 nodes, E=300000 edges, D=256.
// ws layout: [0, N*D) floats = h ; [N*D, N*D+N) floats = deg/dinv (in place).
// Needs ws >= 102.8 MB.

#define NN 100000
#define NE 300000
#define DD 256

typedef __attribute__((ext_vector_type(8))) short short8;
typedef __attribute__((ext_vector_type(4))) short short4v;
typedef __attribute__((ext_vector_type(4))) float f32x4;

// f32 -> bf16 round-to-nearest-even (no NaN special-casing; inputs are finite)
static __device__ __forceinline__ short f2bf(float f) {
  union { float f; unsigned u; } a; a.f = f;
  unsigned r = a.u + 0x7fffu + ((a.u >> 16) & 1u);
  return (short)(r >> 16);
}

__global__ __launch_bounds__(256) void k_zero(float* __restrict__ deg) {
  int i = blockIdx.x * 256 + threadIdx.x;
  if (i < NN) deg[i] = 0.0f;
}

__global__ __launch_bounds__(256) void k_deg(const int* __restrict__ ei,
                                             const float* __restrict__ ew,
                                             float* __restrict__ deg) {
  int e = blockIdx.x * 256 + threadIdx.x;
  if (e < NE) atomicAdd(&deg[ei[NE + e]], ew[e]);
}

__global__ __launch_bounds__(256) void k_dinv(float* __restrict__ deg) {
  int i = blockIdx.x * 256 + threadIdx.x;
  if (i < NN) deg[i] = rsqrtf(deg[i] + 1.0f);
}

// h = x @ W  (bf16 MFMA, f32 accumulate). Also out = dinv^2 * h (self-loop init).
// BM=128, BN=64, K=256 in 4 steps of BK=64. 4 waves: wave covers 64 rows x 32 cols.
__global__ __launch_bounds__(256) void k_gemm(const float* __restrict__ x,
                                              const float* __restrict__ W,
                                              const float* __restrict__ dinv,
                                              float* __restrict__ h,
                                              float* __restrict__ out) {
  __shared__ short Bs[256 * 64];  // W slice [k][c], bf16, 32 KB
  __shared__ short As[128 * 64];  // x chunk [row][k], bf16, XOR-swizzled, 16 KB

  const int t = threadIdx.x;
  const int lane = t & 63;
  const int wid = t >> 6;
  const int row0 = blockIdx.x * 128;
  const int col0 = blockIdx.y * 64;
  const int wrow = (wid >> 1) * 64;   // wave's row offset in tile
  const int wcol = (wid & 1) * 32;    // wave's col offset in tile

  // ---- stage W[:, col0:col0+64] -> Bs (f32 -> bf16), row-major [k][64]
  for (int it = 0; it < 16; ++it) {
    int k = it * 16 + (t >> 4);
    int c = (t & 15) * 4;
    const float4 v = *(const float4*)(W + k * 256 + col0 + c);
    short4v s;
    s[0] = f2bf(v.x); s[1] = f2bf(v.y); s[2] = f2bf(v.z); s[3] = f2bf(v.w);
    *(short4v*)(Bs + k * 64 + c) = s;
  }
  __syncthreads();

  // ---- load all B fragments for this wave into registers.
  // frag (16x16x32): lane holds B[k = ks*32 + 8*(lane>>4)+j][col = lane&15]
  short8 bfrag[8][2];
#pragma unroll
  for (int ks = 0; ks < 8; ++ks)
#pragma unroll
    for (int n = 0; n < 2; ++n) {
      int c = wcol + n * 16 + (lane & 15);
#pragma unroll
      for (int j = 0; j < 8; ++j) {
        int k = ks * 32 + (lane >> 4) * 8 + j;
        bfrag[ks][n][j] = Bs[k * 64 + c];
      }
    }

  f32x4 acc[4][2];
#pragma unroll
  for (int m = 0; m < 4; ++m)
#pragma unroll
    for (int n = 0; n < 2; ++n) acc[m][n] = (f32x4)0.0f;

#pragma unroll
  for (int step = 0; step < 4; ++step) {
    __syncthreads();  // protect As reuse across steps
    // stage A chunk: rows row0..+127, k in [step*64, step*64+64), swizzled
    for (int it = 0; it < 8; ++it) {
      int r = it * 16 + (t >> 4);
      int kk = (t & 15) * 4;  // k offset in elements (4 per thread)
      int grow = row0 + r;
      float4 v = make_float4(0.f, 0.f, 0.f, 0.f);
      if (grow < NN) v = *(const float4*)(x + (size_t)grow * 256 + step * 64 + kk);
      short4v s;
      s[0] = f2bf(v.x); s[1] = f2bf(v.y); s[2] = f2bf(v.z); s[3] = f2bf(v.w);
      int byte = r * 128 + kk * 2;
      byte ^= (r & 7) << 4;  // bank-conflict swizzle
      *(short4v*)((char*)As + byte) = s;
    }
    __syncthreads();

#pragma unroll
    for (int ks2 = 0; ks2 < 2; ++ks2) {
      const int gks = step * 2 + ks2;
      short8 afrag[4];
#pragma unroll
      for (int m = 0; m < 4; ++m) {
        int r = wrow + m * 16 + (lane & 15);
        int byte = r * 128 + (ks2 * 32 + (lane >> 4) * 8) * 2;
        byte ^= (r & 7) << 4;
        afrag[m] = *(short8*)((char*)As + byte);
      }
#pragma unroll
      for (int m = 0; m < 4; ++m)
#pragma unroll
        for (int n = 0; n < 2; ++n)
          acc[m][n] = __builtin_amdgcn_mfma_f32_16x16x32_bf16(
              afrag[m], bfrag[gks][n], acc[m][n], 0, 0, 0);
    }
  }

  // ---- epilogue: h = acc; out = dinv^2 * acc
  // C/D layout: col = lane&15, row = 4*(lane>>4) + j
#pragma unroll
  for (int m = 0; m < 4; ++m) {
    int rbase = wrow + m * 16 + (lane >> 4) * 4;
#pragma unroll
    for (int j = 0; j < 4; ++j) {
      int grow = row0 + rbase + j;
      if (grow >= NN) continue;
      float di = dinv[grow];
      float d2 = di * di;
#pragma unroll
      for (int n = 0; n < 2; ++n) {
        int c = col0 + wcol + n * 16 + (lane & 15);
        float v = acc[m][n][j];
        h[(size_t)grow * 256 + c] = v;
        out[(size_t)grow * 256 + c] = d2 * v;
      }
    }
  }
}

// scatter: out[dst] += dinv[src]*w*dinv[dst] * h[src].  One wave per edge.
__global__ __launch_bounds__(256) void k_scatter(const int* __restrict__ ei,
                                                 const float* __restrict__ ew,
                                                 const float* __restrict__ dinv,
                                                 const float* __restrict__ h,
                                                 float* __restrict__ out) {
  int e = blockIdx.x * 4 + (threadIdx.x >> 6);
  if (e >= NE) return;
  int lane = threadIdx.x & 63;
  int s = ei[e];
  int d = ei[NE + e];
  float c = dinv[s] * ew[e] * dinv[d];
  const float4 v = *(const float4*)(h + (size_t)s * 256 + lane * 4);
  float* o = out + (size_t)d * 256 + lane * 4;
  atomicAdd(o + 0, c * v.x);
  atomicAdd(o + 1, c * v.y);
  atomicAdd(o + 2, c * v.z);
  atomicAdd(o + 3, c * v.w);
}

// finalize: v = out + b; LayerNorm; 0.5*v + 0.5*x; relu. One wave per node.
__global__ __launch_bounds__(256) void k_final(const float* __restrict__ x,
                                               const float* __restrict__ b,
                                               const float* __restrict__ gamma,
                                               const float* __restrict__ beta,
                                               float* __restrict__ out) {
  int node = blockIdx.x * 4 + (threadIdx.x >> 6);
  if (node >= NN) return;
  int lane = threadIdx.x & 63;
  float4 v = *(const float4*)(out + (size_t)node * 256 + lane * 4);
  const float4 bb = *(const float4*)(b + lane * 4);
  v.x += bb.x; v.y += bb.y; v.z += bb.z; v.w += bb.w;
  float s = v.x + v.y + v.z + v.w;
  float ss = v.x * v.x + v.y * v.y + v.z * v.z + v.w * v.w;
#pragma unroll
  for (int off = 32; off > 0; off >>= 1) {
    s += __shfl_xor(s, off);
    ss += __shfl_xor(ss, off);
  }
  const float mu = s * (1.0f / 256.0f);
  const float var = ss * (1.0f / 256.0f) - mu * mu;
  const float inv = rsqrtf(var + 1e-5f);
  const float4 g = *(const float4*)(gamma + lane * 4);
  const float4 be = *(const float4*)(beta + lane * 4);
  const float4 xx = *(const float4*)(x + (size_t)node * 256 + lane * 4);
  float4 r;
  r.x = 0.5f * ((v.x - mu) * inv * g.x + be.x) + 0.5f * xx.x;
  r.y = 0.5f * ((v.y - mu) * inv * g.y + be.y) + 0.5f * xx.y;
  r.z = 0.5f * ((v.z - mu) * inv * g.z + be.z) + 0.5f * xx.z;
  r.w = 0.5f * ((v.w - mu) * inv * g.w + be.w) + 0.5f * xx.w;
  r.x = fmaxf(r.x, 0.0f); r.y = fmaxf(r.y, 0.0f);
  r.z = fmaxf(r.z, 0.0f); r.w = fmaxf(r.w, 0.0f);
  *(float4*)(out + (size_t)node * 256 + lane * 4) = r;
}

extern "C" void kernel_launch(void* const* d_in, const int* in_sizes, int n_in,
                              void* d_out, int out_size, void* d_ws, size_t ws_size,
                              hipStream_t stream) {
  const float* x     = (const float*)d_in[0];
  const int*   ei    = (const int*)d_in[1];
  const float* ew    = (const float*)d_in[2];
  const float* W     = (const float*)d_in[3];
  const float* b     = (const float*)d_in[4];
  const float* gamma = (const float*)d_in[5];
  const float* beta  = (const float*)d_in[6];
  float* out = (float*)d_out;

  float* h   = (float*)d_ws;                 // N*D floats
  float* deg = h + (size_t)NN * DD;          // N floats (deg, then dinv in place)

  k_zero<<<(NN + 255) / 256, 256, 0, stream>>>(deg);
  k_deg<<<(NE + 255) / 256, 256, 0, stream>>>(ei, ew, deg);
  k_dinv<<<(NN + 255) / 256, 256, 0, stream>>>(deg);

  dim3 ggrid((NN + 127) / 128, 4);
  k_gemm<<<ggrid, 256, 0, stream>>>(x, W, deg, h, out);

  k_scatter<<<NE / 4, 256, 0, stream>>>(ei, ew, deg, h, out);
  k_final<<<NN / 4, 256, 0, stream>>>(x, b, gamma, beta, out);
}

// Round 2
// 246.345 us; speedup vs baseline: 4.9287x; 4.9287x over previous
//
#include <hip/hip_runtime.h>

// ResidualGNNLayer: h = x@W; gcn_norm gather-aggregate (CSR built per-call);
// +bias; LayerNorm; 0.5*h+0.5*x; relu.  N=100000, E=300000, D=256.
//
// ws layout (bytes from base):
//   h     : N*256 bf16 (shorts)          51.2 MB
//   dv    : N floats  (deg -> dinv)       0.4 MB
//   cnt   : N ints    (in-degree)         0.4 MB
//   off   : N ints    (CSR offsets)       0.4 MB
//   cur   : N ints    (placement cursor)  0.4 MB
//   bsum  : 512 ints
//   elist : E int2    {src, coef}         2.4 MB
// total ~55.2 MB.

#define NN 100000
#define NE 300000
#define DD 256
#define NB 391  // ceil(NN/256)

typedef __attribute__((ext_vector_type(8))) short short8;
typedef __attribute__((ext_vector_type(4))) short short4v;
typedef __attribute__((ext_vector_type(4))) float f32x4;
typedef __attribute__((ext_vector_type(4))) unsigned short u16x4;

static __device__ __forceinline__ short f2bf(float f) {
  union { float f; unsigned u; } a; a.f = f;
  unsigned r = a.u + 0x7fffu + ((a.u >> 16) & 1u);
  return (short)(r >> 16);
}

static __device__ __forceinline__ float4 bf4_to_f4(u16x4 v) {
  float4 r;
  r.x = __uint_as_float((unsigned)v[0] << 16);
  r.y = __uint_as_float((unsigned)v[1] << 16);
  r.z = __uint_as_float((unsigned)v[2] << 16);
  r.w = __uint_as_float((unsigned)v[3] << 16);
  return r;
}

__global__ __launch_bounds__(256) void k_init(float* __restrict__ dv,
                                              int* __restrict__ cnt) {
  int i = blockIdx.x * 256 + threadIdx.x;
  if (i < NN) { dv[i] = 0.0f; cnt[i] = 0; }
}

__global__ __launch_bounds__(256) void k_hist(const int* __restrict__ ei,
                                              const float* __restrict__ ew,
                                              float* __restrict__ dv,
                                              int* __restrict__ cnt) {
  int e = blockIdx.x * 256 + threadIdx.x;
  if (e < NE) {
    int d = ei[NE + e];
    atomicAdd(&dv[d], ew[e]);
    atomicAdd(&cnt[d], 1);
  }
}

__global__ __launch_bounds__(256) void k_dinv(float* __restrict__ dv) {
  int i = blockIdx.x * 256 + threadIdx.x;
  if (i < NN) dv[i] = rsqrtf(dv[i] + 1.0f);
}

// per-256-chunk exclusive scan; chunk totals to bsum
__global__ __launch_bounds__(256) void k_scan1(const int* __restrict__ cnt,
                                               int* __restrict__ off,
                                               int* __restrict__ bsum) {
  __shared__ int tmp[256];
  int t = threadIdx.x;
  int i = blockIdx.x * 256 + t;
  int v = (i < NN) ? cnt[i] : 0;
  tmp[t] = v;
  __syncthreads();
  for (int o = 1; o < 256; o <<= 1) {
    int u = (t >= o) ? tmp[t - o] : 0;
    __syncthreads();
    tmp[t] += u;
    __syncthreads();
  }
  if (i < NN) off[i] = tmp[t] - v;
  if (t == 255) bsum[blockIdx.x] = tmp[t];
}

// single-block exclusive scan of the 391 chunk totals
__global__ __launch_bounds__(512) void k_scan2(int* __restrict__ bsum) {
  __shared__ int tmp[512];
  int t = threadIdx.x;
  int v = (t < NB) ? bsum[t] : 0;
  tmp[t] = v;
  __syncthreads();
  for (int o = 1; o < 512; o <<= 1) {
    int u = (t >= o) ? tmp[t - o] : 0;
    __syncthreads();
    tmp[t] += u;
    __syncthreads();
  }
  bsum[t] = tmp[t] - v;
}

__global__ __launch_bounds__(256) void k_scan3(int* __restrict__ off,
                                               const int* __restrict__ bsum,
                                               int* __restrict__ cur) {
  int i = blockIdx.x * 256 + threadIdx.x;
  if (i < NN) {
    int o = off[i] + bsum[i >> 8];
    off[i] = o;
    cur[i] = o;
  }
}

// place edges into CSR buckets: elist[pos] = {src, coef}
__global__ __launch_bounds__(256) void k_place(const int* __restrict__ ei,
                                               const float* __restrict__ ew,
                                               const float* __restrict__ dv,
                                               int* __restrict__ cur,
                                               int2* __restrict__ elist) {
  int e = blockIdx.x * 256 + threadIdx.x;
  if (e >= NE) return;
  int s = ei[e];
  int d = ei[NE + e];
  float c = dv[s] * ew[e] * dv[d];
  int pos = atomicAdd(&cur[d], 1);
  elist[pos] = make_int2(s, __float_as_int(c));
}

// h = bf16(x @ W). BM=128, BN=64, K=256 in 4 steps of BK=64. 4 waves.
__global__ __launch_bounds__(256) void k_gemm(const float* __restrict__ x,
                                              const float* __restrict__ W,
                                              short* __restrict__ h) {
  __shared__ short Bs[256 * 64];
  __shared__ short As[128 * 64];

  const int t = threadIdx.x;
  const int lane = t & 63;
  const int wid = t >> 6;
  const int row0 = blockIdx.x * 128;
  const int col0 = blockIdx.y * 64;
  const int wrow = (wid >> 1) * 64;
  const int wcol = (wid & 1) * 32;

  for (int it = 0; it < 16; ++it) {
    int k = it * 16 + (t >> 4);
    int c = (t & 15) * 4;
    const float4 v = *(const float4*)(W + k * 256 + col0 + c);
    short4v s;
    s[0] = f2bf(v.x); s[1] = f2bf(v.y); s[2] = f2bf(v.z); s[3] = f2bf(v.w);
    *(short4v*)(Bs + k * 64 + c) = s;
  }
  __syncthreads();

  short8 bfrag[8][2];
#pragma unroll
  for (int ks = 0; ks < 8; ++ks)
#pragma unroll
    for (int n = 0; n < 2; ++n) {
      int c = wcol + n * 16 + (lane & 15);
#pragma unroll
      for (int j = 0; j < 8; ++j) {
        int k = ks * 32 + (lane >> 4) * 8 + j;
        bfrag[ks][n][j] = Bs[k * 64 + c];
      }
    }

  f32x4 acc[4][2];
#pragma unroll
  for (int m = 0; m < 4; ++m)
#pragma unroll
    for (int n = 0; n < 2; ++n) acc[m][n] = (f32x4)0.0f;

#pragma unroll
  for (int step = 0; step < 4; ++step) {
    __syncthreads();
    for (int it = 0; it < 8; ++it) {
      int r = it * 16 + (t >> 4);
      int kk = (t & 15) * 4;
      int grow = row0 + r;
      float4 v = make_float4(0.f, 0.f, 0.f, 0.f);
      if (grow < NN) v = *(const float4*)(x + (size_t)grow * 256 + step * 64 + kk);
      short4v s;
      s[0] = f2bf(v.x); s[1] = f2bf(v.y); s[2] = f2bf(v.z); s[3] = f2bf(v.w);
      int byte = r * 128 + kk * 2;
      byte ^= (r & 7) << 4;
      *(short4v*)((char*)As + byte) = s;
    }
    __syncthreads();

#pragma unroll
    for (int ks2 = 0; ks2 < 2; ++ks2) {
      const int gks = step * 2 + ks2;
      short8 afrag[4];
#pragma unroll
      for (int m = 0; m < 4; ++m) {
        int r = wrow + m * 16 + (lane & 15);
        int byte = r * 128 + (ks2 * 32 + (lane >> 4) * 8) * 2;
        byte ^= (r & 7) << 4;
        afrag[m] = *(short8*)((char*)As + byte);
      }
#pragma unroll
      for (int m = 0; m < 4; ++m)
#pragma unroll
        for (int n = 0; n < 2; ++n)
          acc[m][n] = __builtin_amdgcn_mfma_f32_16x16x32_bf16(
              afrag[m], bfrag[gks][n], acc[m][n], 0, 0, 0);
    }
  }

#pragma unroll
  for (int m = 0; m < 4; ++m) {
    int rbase = wrow + m * 16 + (lane >> 4) * 4;
#pragma unroll
    for (int j = 0; j < 4; ++j) {
      int grow = row0 + rbase + j;
      if (grow >= NN) continue;
#pragma unroll
      for (int n = 0; n < 2; ++n) {
        int c = col0 + wcol + n * 16 + (lane & 15);
        h[(size_t)grow * 256 + c] = f2bf(acc[m][n][j]);
      }
    }
  }
}

// gather-aggregate + self-loop + bias + LayerNorm + residual + relu.
// One wave per node.
__global__ __launch_bounds__(256) void k_agg(const short* __restrict__ h,
                                             const float* __restrict__ dv,
                                             const int* __restrict__ cnt,
                                             const int* __restrict__ off,
                                             const int2* __restrict__ elist,
                                             const float* __restrict__ x,
                                             const float* __restrict__ b,
                                             const float* __restrict__ gamma,
                                             const float* __restrict__ beta,
                                             float* __restrict__ out) {
  int node = blockIdx.x * 4 + (threadIdx.x >> 6);
  if (node >= NN) return;
  int lane = threadIdx.x & 63;

  const float di = dv[node];
  const float d2 = di * di;
  float4 acc = bf4_to_f4(((const u16x4*)(h + (size_t)node * 256))[lane]);
  acc.x *= d2; acc.y *= d2; acc.z *= d2; acc.w *= d2;

  const int n = cnt[node];
  const int st = off[node];
  for (int j = 0; j < n; ++j) {
    int2 rec = elist[st + j];
    float c = __int_as_float(rec.y);
    float4 v = bf4_to_f4(((const u16x4*)(h + (size_t)rec.x * 256))[lane]);
    acc.x += c * v.x; acc.y += c * v.y; acc.z += c * v.z; acc.w += c * v.w;
  }

  const float4 bb = *(const float4*)(b + lane * 4);
  acc.x += bb.x; acc.y += bb.y; acc.z += bb.z; acc.w += bb.w;

  float s = acc.x + acc.y + acc.z + acc.w;
  float ss = acc.x * acc.x + acc.y * acc.y + acc.z * acc.z + acc.w * acc.w;
#pragma unroll
  for (int o = 32; o > 0; o >>= 1) {
    s += __shfl_xor(s, o);
    ss += __shfl_xor(ss, o);
  }
  const float mu = s * (1.0f / 256.0f);
  const float var = ss * (1.0f / 256.0f) - mu * mu;
  const float inv = rsqrtf(var + 1e-5f);

  const float4 g = *(const float4*)(gamma + lane * 4);
  const float4 be = *(const float4*)(beta + lane * 4);
  const float4 xx = *(const float4*)(x + (size_t)node * 256 + lane * 4);
  float4 r;
  r.x = 0.5f * ((acc.x - mu) * inv * g.x + be.x) + 0.5f * xx.x;
  r.y = 0.5f * ((acc.y - mu) * inv * g.y + be.y) + 0.5f * xx.y;
  r.z = 0.5f * ((acc.z - mu) * inv * g.z + be.z) + 0.5f * xx.z;
  r.w = 0.5f * ((acc.w - mu) * inv * g.w + be.w) + 0.5f * xx.w;
  r.x = fmaxf(r.x, 0.0f); r.y = fmaxf(r.y, 0.0f);
  r.z = fmaxf(r.z, 0.0f); r.w = fmaxf(r.w, 0.0f);
  *(float4*)(out + (size_t)node * 256 + lane * 4) = r;
}

extern "C" void kernel_launch(void* const* d_in, const int* in_sizes, int n_in,
                              void* d_out, int out_size, void* d_ws, size_t ws_size,
                              hipStream_t stream) {
  const float* x     = (const float*)d_in[0];
  const int*   ei    = (const int*)d_in[1];
  const float* ew    = (const float*)d_in[2];
  const float* W     = (const float*)d_in[3];
  const float* b     = (const float*)d_in[4];
  const float* gamma = (const float*)d_in[5];
  const float* beta  = (const float*)d_in[6];
  float* out = (float*)d_out;

  short* h   = (short*)d_ws;                       // N*256 bf16
  float* dv  = (float*)(h + (size_t)NN * DD);      // N floats
  int*   cnt = (int*)(dv + NN);                    // N ints
  int*   off = cnt + NN;                           // N ints
  int*   cur = off + NN;                           // N ints
  int*   bsum = cur + NN;                          // 512 ints
  int2*  elist = (int2*)(bsum + 512);              // NE int2

  k_init<<<NB, 256, 0, stream>>>(dv, cnt);
  k_hist<<<(NE + 255) / 256, 256, 0, stream>>>(ei, ew, dv, cnt);
  k_dinv<<<NB, 256, 0, stream>>>(dv);
  k_scan1<<<NB, 256, 0, stream>>>(cnt, off, bsum);
  k_scan2<<<1, 512, 0, stream>>>(bsum);
  k_scan3<<<NB, 256, 0, stream>>>(off, bsum, cur);
  k_place<<<(NE + 255) / 256, 256, 0, stream>>>(ei, ew, dv, cur, elist);

  dim3 ggrid((NN + 127) / 128, 4);
  k_gemm<<<ggrid, 256, 0, stream>>>(x, W, h);

  k_agg<<<(NN + 3) / 4, 256, 0, stream>>>(h, dv, cnt, off, elist, x, b, gamma, beta, out);
}

// Round 3
// 181.267 us; speedup vs baseline: 6.6982x; 1.3590x over previous
//
#include <hip/hip_runtime.h>

// ResidualGNNLayer: h = x@W; gcn_norm gather-aggregate (CSR built per-call);
// +bias; LayerNorm; 0.5*h+0.5*x; relu.  N=100000, E=300000, D=256.
//
// ws layout:
//   h     : N*256 bf16 (shorts)          51.2 MB
//   dv    : N floats  (deg -> dinv)       0.4 MB
//   cnt   : N ints    (in-degree)         0.4 MB
//   off   : N ints    (CSR offsets)       0.4 MB
//   cur   : N ints    (placement cursor)  0.4 MB
//   bsum  : 512 ints
//   elist : E int2    {src, coef}         2.4 MB
//   Wf    : 65536 shorts (fragment-major bf16 W)  128 KB

#define NN 100000
#define NE 300000
#define DD 256
#define NB 391   // ceil(NN/256)
#define GMB 782  // ceil(NN/128)

typedef __attribute__((ext_vector_type(8))) short short8;
typedef __attribute__((ext_vector_type(4))) short short4v;
typedef __attribute__((ext_vector_type(4))) float f32x4;
typedef __attribute__((ext_vector_type(4))) unsigned short u16x4;

static __device__ __forceinline__ short f2bf(float f) {
  union { float f; unsigned u; } a; a.f = f;
  unsigned r = a.u + 0x7fffu + ((a.u >> 16) & 1u);
  return (short)(r >> 16);
}

static __device__ __forceinline__ float4 bf4_to_f4(u16x4 v) {
  float4 r;
  r.x = __uint_as_float((unsigned)v[0] << 16);
  r.y = __uint_as_float((unsigned)v[1] << 16);
  r.z = __uint_as_float((unsigned)v[2] << 16);
  r.w = __uint_as_float((unsigned)v[3] << 16);
  return r;
}

__global__ __launch_bounds__(256) void k_init(float* __restrict__ dv,
                                              int* __restrict__ cnt) {
  int i = blockIdx.x * 256 + threadIdx.x;
  if (i < NN) { dv[i] = 0.0f; cnt[i] = 0; }
}

__global__ __launch_bounds__(256) void k_hist(const int* __restrict__ ei,
                                              const float* __restrict__ ew,
                                              float* __restrict__ dv,
                                              int* __restrict__ cnt) {
  int e = blockIdx.x * 256 + threadIdx.x;
  if (e < NE) {
    int d = ei[NE + e];
    atomicAdd(&dv[d], ew[e]);
    atomicAdd(&cnt[d], 1);
  }
}

__global__ __launch_bounds__(256) void k_dinv(float* __restrict__ dv) {
  int i = blockIdx.x * 256 + threadIdx.x;
  if (i < NN) dv[i] = rsqrtf(dv[i] + 1.0f);
}

__global__ __launch_bounds__(256) void k_scan1(const int* __restrict__ cnt,
                                               int* __restrict__ off,
                                               int* __restrict__ bsum) {
  __shared__ int tmp[256];
  int t = threadIdx.x;
  int i = blockIdx.x * 256 + t;
  int v = (i < NN) ? cnt[i] : 0;
  tmp[t] = v;
  __syncthreads();
  for (int o = 1; o < 256; o <<= 1) {
    int u = (t >= o) ? tmp[t - o] : 0;
    __syncthreads();
    tmp[t] += u;
    __syncthreads();
  }
  if (i < NN) off[i] = tmp[t] - v;
  if (t == 255) bsum[blockIdx.x] = tmp[t];
}

__global__ __launch_bounds__(512) void k_scan2(int* __restrict__ bsum) {
  __shared__ int tmp[512];
  int t = threadIdx.x;
  int v = (t < NB) ? bsum[t] : 0;
  tmp[t] = v;
  __syncthreads();
  for (int o = 1; o < 512; o <<= 1) {
    int u = (t >= o) ? tmp[t - o] : 0;
    __syncthreads();
    tmp[t] += u;
    __syncthreads();
  }
  bsum[t] = tmp[t] - v;
}

__global__ __launch_bounds__(256) void k_scan3(int* __restrict__ off,
                                               const int* __restrict__ bsum,
                                               int* __restrict__ cur) {
  int i = blockIdx.x * 256 + threadIdx.x;
  if (i < NN) {
    int o = off[i] + bsum[i >> 8];
    off[i] = o;
    cur[i] = o;
  }
}

__global__ __launch_bounds__(256) void k_place(const int* __restrict__ ei,
                                               const float* __restrict__ ew,
                                               const float* __restrict__ dv,
                                               int* __restrict__ cur,
                                               int2* __restrict__ elist) {
  int e = blockIdx.x * 256 + threadIdx.x;
  if (e >= NE) return;
  int s = ei[e];
  int d = ei[NE + e];
  float c = dv[s] * ew[e] * dv[d];
  int pos = atomicAdd(&cur[d], 1);
  elist[pos] = make_int2(s, __float_as_int(c));
}

// Pre-pack W (f32 [k][c]) into fragment-major bf16 Wf:
// short index = ((k>>5)*16 + (c>>4))*512 + ((c&15) + ((k>>3)&3)*16)*8 + (k&7)
__global__ __launch_bounds__(256) void k_wprep(const float* __restrict__ W,
                                               short* __restrict__ Wf) {
  int idx = blockIdx.x * 256 + threadIdx.x;  // 16384 total
  int k = idx >> 6;
  int c4 = idx & 63;
  const float4 v = *(const float4*)(W + k * 256 + c4 * 4);
  float vv[4] = {v.x, v.y, v.z, v.w};
#pragma unroll
  for (int i = 0; i < 4; ++i) {
    int c = c4 * 4 + i;
    int di = ((k >> 5) * 16 + (c >> 4)) * 512 + ((c & 15) + ((k >> 3) & 3) * 16) * 8 + (k & 7);
    Wf[di] = f2bf(vv[i]);
  }
}

// h = bf16(x @ W). BM=128, BN=256 (full), BK=64, 4 K-steps. 8 waves (2x4).
// Only A staged in LDS (16 KB, XOR-swizzled). B fragments read from Wf (L2).
__global__ __launch_bounds__(512) void k_gemm(const float* __restrict__ x,
                                              const short* __restrict__ Wf,
                                              short* __restrict__ h) {
  __shared__ short As[128 * 64];  // 16 KB

  const int t = threadIdx.x;
  const int lane = t & 63;
  const int wid = t >> 6;
  const int row0 = blockIdx.x * 128;
  const int wrow = (wid >> 2) * 64;   // 0 or 64
  const int wcg = (wid & 3) * 4;      // col-group base (16-col units)

  f32x4 acc[4][4];
#pragma unroll
  for (int m = 0; m < 4; ++m)
#pragma unroll
    for (int n = 0; n < 4; ++n) acc[m][n] = (f32x4)0.0f;

#pragma unroll
  for (int step = 0; step < 4; ++step) {
    __syncthreads();
    // stage A: 128 rows x 64 k (f32 -> bf16), 16B chunks, swizzled
#pragma unroll
    for (int it = 0; it < 2; ++it) {
      int p = it * 512 + t;   // 1024 chunks of 8 bf16
      int r = p >> 3;
      int kp = p & 7;
      int grow = row0 + r;
      float4 v0 = make_float4(0.f, 0.f, 0.f, 0.f);
      float4 v1 = v0;
      if (grow < NN) {
        const float* src = x + (size_t)grow * 256 + step * 64 + kp * 8;
        v0 = *(const float4*)(src);
        v1 = *(const float4*)(src + 4);
      }
      short8 s;
      s[0] = f2bf(v0.x); s[1] = f2bf(v0.y); s[2] = f2bf(v0.z); s[3] = f2bf(v0.w);
      s[4] = f2bf(v1.x); s[5] = f2bf(v1.y); s[6] = f2bf(v1.z); s[7] = f2bf(v1.w);
      int byte = (r * 128 + kp * 16) ^ ((r & 7) << 4);
      *(short8*)((char*)As + byte) = s;
    }
    __syncthreads();

#pragma unroll
    for (int ks2 = 0; ks2 < 2; ++ks2) {
      short8 afrag[4];
      short8 bfrag[4];
#pragma unroll
      for (int m = 0; m < 4; ++m) {
        int r = wrow + m * 16 + (lane & 15);
        int byte = (r * 128 + ks2 * 64 + (lane >> 4) * 16) ^ ((r & 7) << 4);
        afrag[m] = *(short8*)((char*)As + byte);
      }
#pragma unroll
      for (int n = 0; n < 4; ++n) {
        size_t fi = (size_t)((step * 2 + ks2) * 16 + wcg + n) * 64 + lane;
        bfrag[n] = *(const short8*)(Wf + fi * 8);
      }
#pragma unroll
      for (int m = 0; m < 4; ++m)
#pragma unroll
        for (int n = 0; n < 4; ++n)
          acc[m][n] = __builtin_amdgcn_mfma_f32_16x16x32_bf16(
              afrag[m], bfrag[n], acc[m][n], 0, 0, 0);
    }
  }

  // epilogue: h = bf16(acc). C/D layout: col = lane&15, row = 4*(lane>>4)+j
#pragma unroll
  for (int m = 0; m < 4; ++m) {
    int rbase = wrow + m * 16 + (lane >> 4) * 4;
#pragma unroll
    for (int j = 0; j < 4; ++j) {
      int grow = row0 + rbase + j;
      if (grow >= NN) continue;
#pragma unroll
      for (int n = 0; n < 4; ++n) {
        int c = (wcg + n) * 16 + (lane & 15);
        h[(size_t)grow * 256 + c] = f2bf(acc[m][n][j]);
      }
    }
  }
}

// gather-aggregate + self-loop + bias + LayerNorm + residual + relu.
__global__ __launch_bounds__(256) void k_agg(const short* __restrict__ h,
                                             const float* __restrict__ dv,
                                             const int* __restrict__ cnt,
                                             const int* __restrict__ off,
                                             const int2* __restrict__ elist,
                                             const float* __restrict__ x,
                                             const float* __restrict__ b,
                                             const float* __restrict__ gamma,
                                             const float* __restrict__ beta,
                                             float* __restrict__ out) {
  int node = blockIdx.x * 4 + (threadIdx.x >> 6);
  if (node >= NN) return;
  int lane = threadIdx.x & 63;

  const float di = dv[node];
  const float d2 = di * di;
  float4 acc = bf4_to_f4(((const u16x4*)(h + (size_t)node * 256))[lane]);
  acc.x *= d2; acc.y *= d2; acc.z *= d2; acc.w *= d2;

  const int n = cnt[node];
  const int st = off[node];
  for (int j = 0; j < n; ++j) {
    int2 rec = elist[st + j];
    float c = __int_as_float(rec.y);
    float4 v = bf4_to_f4(((const u16x4*)(h + (size_t)rec.x * 256))[lane]);
    acc.x += c * v.x; acc.y += c * v.y; acc.z += c * v.z; acc.w += c * v.w;
  }

  const float4 bb = *(const float4*)(b + lane * 4);
  acc.x += bb.x; acc.y += bb.y; acc.z += bb.z; acc.w += bb.w;

  float s = acc.x + acc.y + acc.z + acc.w;
  float ss = acc.x * acc.x + acc.y * acc.y + acc.z * acc.z + acc.w * acc.w;
#pragma unroll
  for (int o = 32; o > 0; o >>= 1) {
    s += __shfl_xor(s, o);
    ss += __shfl_xor(ss, o);
  }
  const float mu = s * (1.0f / 256.0f);
  const float var = ss * (1.0f / 256.0f) - mu * mu;
  const float inv = rsqrtf(var + 1e-5f);

  const float4 g = *(const float4*)(gamma + lane * 4);
  const float4 be = *(const float4*)(beta + lane * 4);
  const float4 xx = *(const float4*)(x + (size_t)node * 256 + lane * 4);
  float4 r;
  r.x = 0.5f * ((acc.x - mu) * inv * g.x + be.x) + 0.5f * xx.x;
  r.y = 0.5f * ((acc.y - mu) * inv * g.y + be.y) + 0.5f * xx.y;
  r.z = 0.5f * ((acc.z - mu) * inv * g.z + be.z) + 0.5f * xx.z;
  r.w = 0.5f * ((acc.w - mu) * inv * g.w + be.w) + 0.5f * xx.w;
  r.x = fmaxf(r.x, 0.0f); r.y = fmaxf(r.y, 0.0f);
  r.z = fmaxf(r.z, 0.0f); r.w = fmaxf(r.w, 0.0f);
  *(float4*)(out + (size_t)node * 256 + lane * 4) = r;
}

extern "C" void kernel_launch(void* const* d_in, const int* in_sizes, int n_in,
                              void* d_out, int out_size, void* d_ws, size_t ws_size,
                              hipStream_t stream) {
  const float* x     = (const float*)d_in[0];
  const int*   ei    = (const int*)d_in[1];
  const float* ew    = (const float*)d_in[2];
  const float* W     = (const float*)d_in[3];
  const float* b     = (const float*)d_in[4];
  const float* gamma = (const float*)d_in[5];
  const float* beta  = (const float*)d_in[6];
  float* out = (float*)d_out;

  short* h   = (short*)d_ws;                       // N*256 bf16
  float* dv  = (float*)(h + (size_t)NN * DD);      // N floats
  int*   cnt = (int*)(dv + NN);                    // N ints
  int*   off = cnt + NN;                           // N ints
  int*   cur = off + NN;                           // N ints
  int*   bsum = cur + NN;                          // 512 ints
  int2*  elist = (int2*)(bsum + 512);              // NE int2
  short* Wf  = (short*)(elist + NE);               // 65536 shorts

  k_init<<<NB, 256, 0, stream>>>(dv, cnt);
  k_hist<<<(NE + 255) / 256, 256, 0, stream>>>(ei, ew, dv, cnt);
  k_dinv<<<NB, 256, 0, stream>>>(dv);
  k_scan1<<<NB, 256, 0, stream>>>(cnt, off, bsum);
  k_scan2<<<1, 512, 0, stream>>>(bsum);
  k_scan3<<<NB, 256, 0, stream>>>(off, bsum, cur);
  k_place<<<(NE + 255) / 256, 256, 0, stream>>>(ei, ew, dv, cur, elist);

  k_wprep<<<64, 256, 0, stream>>>(W, Wf);
  k_gemm<<<GMB, 512, 0, stream>>>(x, Wf, h);

  k_agg<<<(NN + 3) / 4, 256, 0, stream>>>(h, dv, cnt, off, elist, x, b, gamma, beta, out);
}